// Round 21
// baseline (114.242 us; speedup 1.0000x reference)
//
#include <hip/hip_runtime.h>
#include <stdint.h>

namespace {

typedef _Float16 f16x8 __attribute__((ext_vector_type(8)));
typedef __fp16 fp16x2 __attribute__((ext_vector_type(2)));
typedef float f32x16 __attribute__((ext_vector_type(16)));
typedef unsigned short u16x4 __attribute__((ext_vector_type(4)));

constexpr int BATCH = 16;
constexpr int LQ = 2048;
constexpr int LK = 2048;
constexpr int DIM = 64;
constexpr float SCALE = 0.125f;  // 1/sqrt(64)

// d_ws byte offsets (flag at 0)
constexpr size_t WS_KF = 1ull << 20;  // 4 MB fp16 K, fragment-ordered
constexpr size_t WS_VT = 6ull << 20;  // 4 MB fp16 V, fragment-ordered

__device__ inline unsigned short f2h_bits(float x) {  // RNE fp32->fp16
  _Float16 h = (_Float16)x;
  union { _Float16 h; unsigned short u; } c;
  c.h = h;
  return c.u;
}
__device__ inline int cvt_pk_f16(float lo, float hi) {  // packed RTZ
  union { fp16x2 h2; int i; } u;
  u.h2 = __builtin_amdgcn_cvt_pkrtz(lo, hi);
  return u.i;
}
__device__ inline unsigned pack8(uint4 x0, uint4 x1) {  // 8 words -> 8 bits
  return (unsigned)(x0.x != 0u) | ((unsigned)(x0.y != 0u) << 1) |
         ((unsigned)(x0.z != 0u) << 2) | ((unsigned)(x0.w != 0u) << 3) |
         ((unsigned)(x1.x != 0u) << 4) | ((unsigned)(x1.y != 0u) << 5) |
         ((unsigned)(x1.z != 0u) << 6) | ((unsigned)(x1.w != 0u) << 7);
}
__device__ inline uint32_t pack32u8(uint4 x0, uint4 x1) {  // 32 B -> 32 bits
  uint32_t w32 = 0;
#pragma unroll
  for (int q = 0; q < 4; ++q) {
    uint32_t w0 = (&x0.x)[q], w1 = (&x1.x)[q];
    uint32_t nib0 = (unsigned)((w0 & 0xFFu) != 0u) |
                    ((unsigned)(((w0 >> 8) & 0xFFu) != 0u) << 1) |
                    ((unsigned)(((w0 >> 16) & 0xFFu) != 0u) << 2) |
                    ((unsigned)(((w0 >> 24) & 0xFFu) != 0u) << 3);
    uint32_t nib1 = (unsigned)((w1 & 0xFFu) != 0u) |
                    ((unsigned)(((w1 >> 8) & 0xFFu) != 0u) << 1) |
                    ((unsigned)(((w1 >> 16) & 0xFFu) != 0u) << 2) |
                    ((unsigned)(((w1 >> 24) & 0xFFu) != 0u) << 3);
    w32 |= (nib0 << (q * 4)) | (nib1 << (16 + q * 4));
  }
  return w32;
}

// mfma_f32_32x32x16_f16: A m=l&31 k=(l>>5)*8+e; B n=l&31 same k;
// C/D col n=l&31, row m=(reg&3)+8*(reg>>2)+4*(l>>5)  [verified R8-R20 PASS]

// Prep: [0,2048) K frags fp16, [2048,2560) V frags fp16 (verified R13-R20);
// block 2560 = mask dtype detect.
__global__ __launch_bounds__(256) void prep_kv(
    const float* __restrict__ kp, const float* __restrict__ vp,
    const uint32_t* __restrict__ maskp, int* __restrict__ flag,
    unsigned short* __restrict__ kf, unsigned short* __restrict__ vt) {
  const int blk = blockIdx.x;
  if (blk < 2048) {
    int idx = blk * 256 + threadIdx.x;
    int b = idx >> 15;
    int rem = idx & 32767;
    int r = rem >> 4;
    int d0 = (rem & 15) * 4;
    float4 kv = *(const float4*)(kp + ((size_t)b * LK + r) * DIM + d0);
    u16x4 hv;
#pragma unroll
    for (int j = 0; j < 4; ++j) hv[j] = f2h_bits((&kv.x)[j]);
    int T = r >> 6;
    int rin = r & 63;
    int f = rin >> 5;
    int m = rin & 31;
    int s = d0 >> 4;
    int hi = (d0 >> 3) & 1;
    int e0 = d0 & 7;
    size_t off =
        ((((size_t)(b * 32 + T) * 2 + f) * 4 + s) * 64 + (hi * 32 + m)) * 8 +
        e0;
    *(u16x4*)(kf + off) = hv;
  } else if (blk < 2560) {
    int idx = (blk - 2048) * 256 + threadIdx.x;
    int b = idx >> 13;
    int rem = idx & 8191;
    int kq = rem >> 4;
    int dq = rem & 15;
    int k0 = kq * 4;
    int T = k0 >> 6;
    int kin = k0 & 63;
    const float* vg = vp + ((size_t)b * LK + k0) * DIM + dq * 4;
    unsigned short tmp[4][4];
#pragma unroll
    for (int j = 0; j < 4; ++j) {
      float4 vf = *(const float4*)(vg + j * DIM);
#pragma unroll
      for (int i2 = 0; i2 < 4; ++i2) tmp[j][i2] = f2h_bits((&vf.x)[i2]);
    }
    int ks = kin >> 4;
    int hi = (kin >> 3) & 1;
    int e0 = kin & 7;
#pragma unroll
    for (int j2 = 0; j2 < 4; ++j2) {
      int d = dq * 4 + j2;
      int nb = d >> 5;
      u16x4 od = {tmp[0][j2], tmp[1][j2], tmp[2][j2], tmp[3][j2]};
      size_t off = ((((size_t)(b * 32 + T) * 2 + nb) * 4 + ks) * 64 +
                    (hi * 32 + (d & 31))) * 8 + e0;
      *(u16x4*)(vt + off) = od;
    }
  } else {
    __shared__ int bad;
    if (threadIdx.x == 0) bad = 0;
    __syncthreads();
    int my = 0;
    for (int i = threadIdx.x; i < 4096; i += 256) {
      uint32_t w = maskp[i];
      if (w > 1u && w != 0x3F800000u) my = 1;
    }
    if (my) atomicOr(&bad, 1);
    __syncthreads();
    if (threadIdx.x == 0) *flag = bad;
  }
}

// Main: 512 blocks x 512 thr, 1 block/CU (8 waves/CU -> 256-VGPR budget;
// R17's identical structure at (512,2) had a 128 cap and spilled -- that
// was its only diagnosed defect). Wave specialization: waves 0-3 compute
// (k-quarters, R15 core), waves 4-7 stream group B's mask during
// compute(A). Separate waves = separate vmcnt counters = stream VMEM
// never blocks V/K consumption (fixes R16's ordering stall).
__global__ __launch_bounds__(512, 1) void attn_mfma(
    const float* __restrict__ qp, const unsigned short* __restrict__ kf_g,
    const unsigned short* __restrict__ vt_g,
    const uint32_t* __restrict__ maskp, const int* __restrict__ flagp,
    float* __restrict__ out) {
  __shared__ __align__(16) unsigned char NB[2][8192];
  __shared__ __align__(16) float X[3 * 64 * 33];
  __shared__ float den_s[32];

  const int tid = threadIdx.x;
  const int w = tid >> 6;         // 0..7
  const int isComp = (w < 4);
  const int h = w & 3;            // k-quarter for compute waves
  const int l = tid & 63;
  const int m31 = l & 31;
  const int hi = l >> 5;
  const int xcd = blockIdx.x & 7;
  const int idx = blockIdx.x >> 3;  // 0..63
  const int b = xcd * 2 + (idx >> 5);
  const int qb64 = (idx & 31) * 64;
  const int isU8 = *flagp;

  // ---- phase 0: ALL 8 waves stream group A -> NB[0] ----
  {
    const size_t mbase = ((size_t)b * LQ + qb64) * LK;
    if (!isU8) {
      const uint32_t* mg = maskp + mbase;
#pragma unroll 4
      for (int i = 0; i < 16; ++i) {
        const int u = i * 512 + tid;  // 8192 nib-bytes
        const uint32_t* src = mg + (size_t)u * 8;
        uint4 x0 = *(const uint4*)(src);
        uint4 x1 = *(const uint4*)(src + 4);
        NB[0][(((u >> 3) & 31) * 32 + (u >> 8)) * 8 + (u & 7)] =
            (unsigned char)pack8(x0, x1);
      }
    } else {
      const uint8_t* mg = (const uint8_t*)maskp + mbase;
#pragma unroll 4
      for (int i = 0; i < 4; ++i) {
        const int c = i * 512 + tid;  // 2048 chunks
        const uint8_t* src = mg + (size_t)c * 32;
        uint4 x0 = *(const uint4*)(src);
        uint4 x1 = *(const uint4*)(src + 16);
        const int u0 = c * 4;
        *(uint32_t*)&NB[0][(((u0 >> 3) & 31) * 32 + (u0 >> 8)) * 8 +
                           (u0 & 7)] = pack32u8(x0, x1);
      }
    }
  }
  __syncthreads();

  // Fragment bases (halfword): tile stride 4096; f-block stride 2048.
  const unsigned short* kb =
      kf_g + (size_t)(b * 32 + h * 8) * 4096 + (size_t)l * 8;
  const unsigned short* vbp =
      vt_g + (size_t)(b * 32 + h * 8) * 4096 + (size_t)l * 8;

  for (int g = 0; g < 2; ++g) {
    f32x16 oA = (f32x16)(0.f), oB = (f32x16)(0.f);
    float denA = 0.f, denB = 0.f;

    if (isComp) {
      // ================= compute waves: R15-verified core =================
      const int qrow = qb64 + g * 32 + m31;
      f16x8 qf[4];
      {
        const float* qr = qp + ((size_t)b * LQ + qrow) * DIM;
#pragma unroll
        for (int s = 0; s < 4; ++s) {
#pragma unroll
          for (int j2 = 0; j2 < 2; ++j2) {
            float4 x = *(const float4*)(qr + s * 16 + hi * 8 + j2 * 4);
#pragma unroll
            for (int j = 0; j < 4; ++j)
              qf[s][j2 * 4 + j] = (_Float16)(&x.x)[j];
          }
        }
      }
      f16x8 kc0[4], kc1[4], vb0[4], vb1[4];
#pragma unroll
      for (int s = 0; s < 4; ++s) {
        kc0[s] = *(const f16x8*)(kb + s * 512);
        kc1[s] = *(const f16x8*)(kb + 2048 + s * 512);
      }

      for (int t = 0; t < 8; ++t) {  // rolled
        const size_t tb = (size_t)t * 4096;
        const unsigned long long mb =
            *(const unsigned long long*)&NB[g][((h * 8 + t) * 32 + m31) * 8];
        const uint32_t mb0 = (uint32_t)mb;
        const uint32_t mb1 = (uint32_t)(mb >> 32);
#pragma unroll
        for (int s = 0; s < 4; ++s) {
          vb0[s] = *(const f16x8*)(vbp + tb + s * 512);
          vb1[s] = *(const f16x8*)(vbp + tb + 2048 + s * 512);
        }

        f32x16 sA = (f32x16)(0.f), sB = (f32x16)(0.f);
        __builtin_amdgcn_s_setprio(1);
#pragma unroll
        for (int s = 0; s < 4; ++s) {
          sA = __builtin_amdgcn_mfma_f32_32x32x16_f16(kc0[s], qf[s], sA, 0, 0,
                                                      0);
          sB = __builtin_amdgcn_mfma_f32_32x32x16_f16(kc1[s], qf[s], sB, 0, 0,
                                                      0);
        }
        __builtin_amdgcn_s_setprio(0);

        if (t < 7) {
#pragma unroll
          for (int s = 0; s < 4; ++s) {
            kc0[s] = *(const f16x8*)(kb + tb + 4096 + s * 512);
            kc1[s] = *(const f16x8*)(kb + tb + 4096 + 2048 + s * 512);
          }
        }

        const int hi4 = hi * 4;
#pragma unroll
        for (int reg = 0; reg < 16; ++reg) {
          const int crow = (reg & 3) + 8 * (reg >> 2);
          float eA =
              ((mb0 >> (crow + hi4)) & 1u) ? 1.0f : __expf(sA[reg] * SCALE);
          float eB =
              ((mb1 >> (crow + hi4)) & 1u) ? 1.0f : __expf(sB[reg] * SCALE);
          denA += eA;
          denB += eB;
          sA[reg] = eA;
          sB[reg] = eB;
        }

#define PV_STEP(SV, A_, KS_)                                                \
  do {                                                                      \
    int c0x = cvt_pk_f16(SV[8 * A_ + 0], SV[8 * A_ + 1]);                   \
    int c1x = cvt_pk_f16(SV[8 * A_ + 2], SV[8 * A_ + 3]);                   \
    int c0y = cvt_pk_f16(SV[8 * A_ + 4], SV[8 * A_ + 5]);                   \
    int c1y = cvt_pk_f16(SV[8 * A_ + 6], SV[8 * A_ + 7]);                   \
    asm("v_permlane32_swap_b32 %0, %1" : "+v"(c0x), "+v"(c0y));             \
    asm("v_permlane32_swap_b32 %0, %1" : "+v"(c1x), "+v"(c1y));             \
    union { int d[4]; f16x8 v; } pa_;                                       \
    pa_.d[0] = c0x; pa_.d[1] = c1x; pa_.d[2] = c0y; pa_.d[3] = c1y;         \
    oA = __builtin_amdgcn_mfma_f32_32x32x16_f16(pa_.v, vb0[KS_], oA, 0, 0,  \
                                                0);                         \
    oB = __builtin_amdgcn_mfma_f32_32x32x16_f16(pa_.v, vb1[KS_], oB, 0, 0,  \
                                                0);                         \
  } while (0)

        __builtin_amdgcn_s_setprio(1);
        PV_STEP(sA, 0, 0);
        PV_STEP(sA, 1, 1);
        PV_STEP(sB, 0, 2);
        PV_STEP(sB, 1, 3);
        __builtin_amdgcn_s_setprio(0);
#undef PV_STEP
      }
    } else if (g == 0) {
      // ============ streamer waves: pack group B -> NB[1] ============
      const int sid = tid & 255;
      const size_t mbaseB = ((size_t)b * LQ + qb64 + 32) * LK;
      if (!isU8) {
        const uint32_t* mg = maskp + mbaseB;
#pragma unroll 4
        for (int i = 0; i < 32; ++i) {
          const int u = i * 256 + sid;
          const uint32_t* src = mg + (size_t)u * 8;
          uint4 x0 = *(const uint4*)(src);
          uint4 x1 = *(const uint4*)(src + 4);
          NB[1][(((u >> 3) & 31) * 32 + (u >> 8)) * 8 + (u & 7)] =
              (unsigned char)pack8(x0, x1);
        }
      } else {
        const uint8_t* mg = (const uint8_t*)maskp + mbaseB;
#pragma unroll 4
        for (int i = 0; i < 8; ++i) {
          const int c = i * 256 + sid;
          const uint8_t* src = mg + (size_t)c * 32;
          uint4 x0 = *(const uint4*)(src);
          uint4 x1 = *(const uint4*)(src + 16);
          const int u0 = c * 4;
          *(uint32_t*)&NB[1][(((u0 >> 3) & 31) * 32 + (u0 >> 8)) * 8 +
                             (u0 & 7)] = pack32u8(x0, x1);
        }
      }
    }

    // ---- epilogue for group g (block-wide barriers, uniform count) ----
    float den = denA + denB;
    __syncthreads();  // compute done; NB[1] ready for g=1
    if (isComp && h > 0) {
      float* xp = X + ((size_t)((h - 1) * 64 + l)) * 33;
#pragma unroll
      for (int reg = 0; reg < 16; ++reg) {
        xp[reg] = oA[reg];
        xp[16 + reg] = oB[reg];
      }
      xp[32] = den;
    }
    __syncthreads();
    if (isComp && h == 0) {
#pragma unroll
      for (int p = 0; p < 3; ++p) {
        const float* xp = X + ((size_t)(p * 64 + l)) * 33;
#pragma unroll
        for (int reg = 0; reg < 16; ++reg) {
          oA[reg] += xp[reg];
          oB[reg] += xp[16 + reg];
        }
        den += xp[32];
      }
      den += __shfl_xor(den, 32);
      if (l < 32) den_s[m31] = 1.0f / den;
      float* ob = out + ((size_t)b * LQ + qb64 + g * 32) * DIM;
#pragma unroll
      for (int reg = 0; reg < 16; ++reg) {
        const int qr2 = (reg & 3) + 8 * (reg >> 2) + hi * 4;
        const float inv = den_s[qr2];
        ob[qr2 * DIM + m31] = oA[reg] * inv;
        ob[qr2 * DIM + 32 + m31] = oB[reg] * inv;
      }
    }
  }
}

}  // namespace

extern "C" void kernel_launch(void* const* d_in, const int* in_sizes, int n_in,
                              void* d_out, int out_size, void* d_ws,
                              size_t ws_size, hipStream_t stream) {
  const float* q = (const float*)d_in[0];
  const float* k = (const float*)d_in[1];
  const float* v = (const float*)d_in[2];
  const uint32_t* mask = (const uint32_t*)d_in[3];
  float* out = (float*)d_out;
  int* flag = (int*)d_ws;
  unsigned short* kf_g = (unsigned short*)((char*)d_ws + WS_KF);
  unsigned short* vt_g = (unsigned short*)((char*)d_ws + WS_VT);

  prep_kv<<<2561, 256, 0, stream>>>(k, v, mask, flag, kf_g, vt_g);
  attn_mfma<<<dim3(512), 512, 0, stream>>>(q, kf_g, vt_g, mask, flag, out);
}

// Round 22
// 91.119 us; speedup vs baseline: 1.2538x; 1.2538x over previous
//
#include <hip/hip_runtime.h>
#include <stdint.h>

namespace {

typedef _Float16 f16x8 __attribute__((ext_vector_type(8)));
typedef __fp16 fp16x2 __attribute__((ext_vector_type(2)));
typedef float f32x16 __attribute__((ext_vector_type(16)));
typedef unsigned short u16x4 __attribute__((ext_vector_type(4)));

constexpr int BATCH = 16;
constexpr int LQ = 2048;
constexpr int LK = 2048;
constexpr int DIM = 64;
constexpr float SCALE = 0.125f;  // 1/sqrt(64)

// d_ws byte offsets (flag at 0)
constexpr size_t WS_KF = 1ull << 20;  // 4 MB fp16 K, fragment-ordered
constexpr size_t WS_VT = 6ull << 20;  // 4 MB fp16 V, fragment-ordered

__device__ inline unsigned short f2h_bits(float x) {  // RNE fp32->fp16
  _Float16 h = (_Float16)x;
  union { _Float16 h; unsigned short u; } c;
  c.h = h;
  return c.u;
}
__device__ inline int cvt_pk_f16(float lo, float hi) {  // packed RTZ
  union { fp16x2 h2; int i; } u;
  u.h2 = __builtin_amdgcn_cvt_pkrtz(lo, hi);
  return u.i;
}
__device__ inline unsigned pack8(uint4 x0, uint4 x1) {  // 8 words -> 8 bits
  return (unsigned)(x0.x != 0u) | ((unsigned)(x0.y != 0u) << 1) |
         ((unsigned)(x0.z != 0u) << 2) | ((unsigned)(x0.w != 0u) << 3) |
         ((unsigned)(x1.x != 0u) << 4) | ((unsigned)(x1.y != 0u) << 5) |
         ((unsigned)(x1.z != 0u) << 6) | ((unsigned)(x1.w != 0u) << 7);
}
__device__ inline uint32_t pack32u8(uint4 x0, uint4 x1) {  // 32 B -> 32 bits
  uint32_t w32 = 0;
#pragma unroll
  for (int q = 0; q < 4; ++q) {
    uint32_t w0 = (&x0.x)[q], w1 = (&x1.x)[q];
    uint32_t nib0 = (unsigned)((w0 & 0xFFu) != 0u) |
                    ((unsigned)(((w0 >> 8) & 0xFFu) != 0u) << 1) |
                    ((unsigned)(((w0 >> 16) & 0xFFu) != 0u) << 2) |
                    ((unsigned)(((w0 >> 24) & 0xFFu) != 0u) << 3);
    uint32_t nib1 = (unsigned)((w1 & 0xFFu) != 0u) |
                    ((unsigned)(((w1 >> 8) & 0xFFu) != 0u) << 1) |
                    ((unsigned)(((w1 >> 16) & 0xFFu) != 0u) << 2) |
                    ((unsigned)(((w1 >> 24) & 0xFFu) != 0u) << 3);
    w32 |= (nib0 << (q * 4)) | (nib1 << (16 + q * 4));
  }
  return w32;
}

// mfma_f32_32x32x16_f16: A m=l&31 k=(l>>5)*8+e; B n=l&31 same k;
// C/D col n=l&31, row m=(reg&3)+8*(reg>>2)+4*(l>>5)  [verified R8-R21 PASS]

// Prep (grid-stride, 321 blocks): [0,256) K frags x8, [256,320) V frags x8,
// block 320 = mask dtype detect. Same per-element math as R13-R21 (PASS).
__global__ __launch_bounds__(256) void prep_kv(
    const float* __restrict__ kp, const float* __restrict__ vp,
    const uint32_t* __restrict__ maskp, int* __restrict__ flag,
    unsigned short* __restrict__ kf, unsigned short* __restrict__ vt) {
  const int blk = blockIdx.x;
  if (blk < 256) {
#pragma unroll
    for (int it = 0; it < 8; ++it) {
      int idx = (blk * 8 + it) * 256 + threadIdx.x;
      int b = idx >> 15;
      int rem = idx & 32767;
      int r = rem >> 4;
      int d0 = (rem & 15) * 4;
      float4 kv = *(const float4*)(kp + ((size_t)b * LK + r) * DIM + d0);
      u16x4 hv;
#pragma unroll
      for (int j = 0; j < 4; ++j) hv[j] = f2h_bits((&kv.x)[j]);
      int T = r >> 6;
      int rin = r & 63;
      int f = rin >> 5;
      int m = rin & 31;
      int s = d0 >> 4;
      int hi = (d0 >> 3) & 1;
      int e0 = d0 & 7;
      size_t off =
          ((((size_t)(b * 32 + T) * 2 + f) * 4 + s) * 64 + (hi * 32 + m)) * 8 +
          e0;
      *(u16x4*)(kf + off) = hv;
    }
  } else if (blk < 320) {
#pragma unroll
    for (int it = 0; it < 8; ++it) {
      int idx = ((blk - 256) * 8 + it) * 256 + threadIdx.x;
      int b = idx >> 13;
      int rem = idx & 8191;
      int kq = rem >> 4;
      int dq = rem & 15;
      int k0 = kq * 4;
      int T = k0 >> 6;
      int kin = k0 & 63;
      const float* vg = vp + ((size_t)b * LK + k0) * DIM + dq * 4;
      unsigned short tmp[4][4];
#pragma unroll
      for (int j = 0; j < 4; ++j) {
        float4 vf = *(const float4*)(vg + j * DIM);
#pragma unroll
        for (int i2 = 0; i2 < 4; ++i2) tmp[j][i2] = f2h_bits((&vf.x)[i2]);
      }
      int ks = kin >> 4;
      int hi = (kin >> 3) & 1;
      int e0 = kin & 7;
#pragma unroll
      for (int j2 = 0; j2 < 4; ++j2) {
        int d = dq * 4 + j2;
        int nb = d >> 5;
        u16x4 od = {tmp[0][j2], tmp[1][j2], tmp[2][j2], tmp[3][j2]};
        size_t off = ((((size_t)(b * 32 + T) * 2 + nb) * 4 + ks) * 64 +
                      (hi * 32 + (d & 31))) * 8 + e0;
        *(u16x4*)(vt + off) = od;
      }
    }
  } else {
    __shared__ int bad;
    if (threadIdx.x == 0) bad = 0;
    __syncthreads();
    int my = 0;
    for (int i = threadIdx.x; i < 4096; i += 256) {
      uint32_t w = maskp[i];
      if (w > 1u && w != 0x3F800000u) my = 1;
    }
    if (my) atomicOr(&bad, 1);
    __syncthreads();
    if (threadIdx.x == 0) *flag = bad;
  }
}

// Main: byte-identical to R15 (83.2us best). 1024 blocks x 256 thr,
// 2 blocks/CU. Phase 0: linear-stream own 32 mask rows -> 8KB LDS bits;
// compute: fp16 pipelined swapped-QK^T core (R13-verified).
__global__ __launch_bounds__(256, 2) void attn_mfma(
    const float* __restrict__ qp, const unsigned short* __restrict__ kf_g,
    const unsigned short* __restrict__ vt_g,
    const uint32_t* __restrict__ maskp, const int* __restrict__ flagp,
    float* __restrict__ out) {
  // arena alias: compute = NB bytes [T:32][row:32][e2:8] (8 KB);
  // epilogue (after barrier) = X float[3*64*33] (25.3 KB).
  __shared__ __align__(16) unsigned char arena[3 * 64 * 33 * 4];
  __shared__ float den_s[32];
  unsigned char* NB = arena;
  float* X = (float*)arena;

  const int tid = threadIdx.x;
  const int h = tid >> 6;  // k-quarter
  const int l = tid & 63;
  const int m31 = l & 31;
  const int hi = l >> 5;
  const int xcd = blockIdx.x & 7;
  const int idx = blockIdx.x >> 3;
  const int b = xcd * 2 + (idx >> 6);
  const int qbase = (idx & 63) * 32;
  const int qrow = qbase + m31;
  const int isU8 = *flagp;

  // ---- phase 0: linear-stream own 32 mask rows -> NB bits ----
  {
    const size_t mbase = ((size_t)b * LQ + qbase) * LK;  // element index
    if (!isU8) {
      const uint32_t* mg = maskp + mbase;
#pragma unroll 4
      for (int i = 0; i < 32; ++i) {
        const int u = i * 256 + tid;  // nib-byte index 0..8191
        const uint32_t* src = mg + (size_t)u * 8;
        uint4 x0 = *(const uint4*)(src);
        uint4 x1 = *(const uint4*)(src + 4);
        NB[(((u >> 3) & 31) * 32 + (u >> 8)) * 8 + (u & 7)] =
            (unsigned char)pack8(x0, x1);
      }
    } else {
      const uint8_t* mg = (const uint8_t*)maskp + mbase;
#pragma unroll 4
      for (int i = 0; i < 8; ++i) {
        const int c = i * 256 + tid;  // 32-byte chunk 0..2047
        const uint8_t* src = mg + (size_t)c * 32;
        uint4 x0 = *(const uint4*)(src);
        uint4 x1 = *(const uint4*)(src + 16);
        const int u0 = c * 4;
        *(uint32_t*)&NB[(((u0 >> 3) & 31) * 32 + (u0 >> 8)) * 8 + (u0 & 7)] =
            pack32u8(x0, x1);
      }
    }
  }
  __syncthreads();

  // Fragment bases (halfword): tile stride 4096; f-block stride 2048.
  const unsigned short* kb =
      kf_g + (size_t)(b * 32 + h * 8) * 4096 + (size_t)l * 8;
  const unsigned short* vb =
      vt_g + (size_t)(b * 32 + h * 8) * 4096 + (size_t)l * 8;

  // ---- Q fragments (fp16), B-operand ----
  f16x8 qf[4];
  {
    const float* qr = qp + ((size_t)b * LQ + qrow) * DIM;
#pragma unroll
    for (int s = 0; s < 4; ++s) {
#pragma unroll
      for (int j2 = 0; j2 < 2; ++j2) {
        float4 x = *(const float4*)(qr + s * 16 + hi * 8 + j2 * 4);
#pragma unroll
        for (int j = 0; j < 4; ++j) qf[s][j2 * 4 + j] = (_Float16)(&x.x)[j];
      }
    }
  }

  f32x16 oA = (f32x16)(0.f), oB = (f32x16)(0.f);
  float denA = 0.f, denB = 0.f;

  f16x8 kc0[4], kc1[4];  // K frags, current tile
  f16x8 vb0[4], vb1[4];  // V frags, current tile

  // prologue: K(0)
#pragma unroll
  for (int s = 0; s < 4; ++s) {
    kc0[s] = *(const f16x8*)(kb + s * 512);
    kc1[s] = *(const f16x8*)(kb + 2048 + s * 512);
  }

  for (int t = 0; t < 8; ++t) {  // rolled
    const size_t tb = (size_t)t * 4096;
    // mask bits for this tile (LDS u64, 2-way broadcast)
    const unsigned long long mb =
        *(const unsigned long long*)&NB[((h * 8 + t) * 32 + m31) * 8];
    const uint32_t mb0 = (uint32_t)mb;
    const uint32_t mb1 = (uint32_t)(mb >> 32);
    // V(t): in flight under QK(t)
#pragma unroll
    for (int s = 0; s < 4; ++s) {
      vb0[s] = *(const f16x8*)(vb + tb + s * 512);
      vb1[s] = *(const f16x8*)(vb + tb + 2048 + s * 512);
    }

    // ---- QK^T (fp16 single term) ----
    f32x16 sA = (f32x16)(0.f), sB = (f32x16)(0.f);
    __builtin_amdgcn_s_setprio(1);
#pragma unroll
    for (int s = 0; s < 4; ++s) {
      sA = __builtin_amdgcn_mfma_f32_32x32x16_f16(kc0[s], qf[s], sA, 0, 0, 0);
      sB = __builtin_amdgcn_mfma_f32_32x32x16_f16(kc1[s], qf[s], sB, 0, 0, 0);
    }
    __builtin_amdgcn_s_setprio(0);

    // K(t+1): kc dead after QK issue; loads land under exp+PV
    if (t < 7) {
#pragma unroll
      for (int s = 0; s < 4; ++s) {
        kc0[s] = *(const f16x8*)(kb + tb + 4096 + s * 512);
        kc1[s] = *(const f16x8*)(kb + tb + 4096 + 2048 + s * 512);
      }
    }

    // ---- mask + exp in-register ----
    const int hi4 = hi * 4;
#pragma unroll
    for (int reg = 0; reg < 16; ++reg) {
      const int crow = (reg & 3) + 8 * (reg >> 2);
      float eA = ((mb0 >> (crow + hi4)) & 1u) ? 1.0f : __expf(sA[reg] * SCALE);
      float eB = ((mb1 >> (crow + hi4)) & 1u) ? 1.0f : __expf(sB[reg] * SCALE);
      denA += eA;
      denB += eB;
      sA[reg] = eA;
      sB[reg] = eB;
    }

    // ---- P->A frags (cvt_pkrtz + permlane32_swap) + PV ----
#define PV_STEP(SV, A_, KS_)                                                \
  do {                                                                      \
    int c0x = cvt_pk_f16(SV[8 * A_ + 0], SV[8 * A_ + 1]);                   \
    int c1x = cvt_pk_f16(SV[8 * A_ + 2], SV[8 * A_ + 3]);                   \
    int c0y = cvt_pk_f16(SV[8 * A_ + 4], SV[8 * A_ + 5]);                   \
    int c1y = cvt_pk_f16(SV[8 * A_ + 6], SV[8 * A_ + 7]);                   \
    asm("v_permlane32_swap_b32 %0, %1" : "+v"(c0x), "+v"(c0y));             \
    asm("v_permlane32_swap_b32 %0, %1" : "+v"(c1x), "+v"(c1y));             \
    union { int d[4]; f16x8 v; } pa_;                                       \
    pa_.d[0] = c0x; pa_.d[1] = c1x; pa_.d[2] = c0y; pa_.d[3] = c1y;         \
    oA = __builtin_amdgcn_mfma_f32_32x32x16_f16(pa_.v, vb0[KS_], oA, 0, 0,  \
                                                0);                         \
    oB = __builtin_amdgcn_mfma_f32_32x32x16_f16(pa_.v, vb1[KS_], oB, 0, 0,  \
                                                0);                         \
  } while (0)

    __builtin_amdgcn_s_setprio(1);
    PV_STEP(sA, 0, 0);
    PV_STEP(sA, 1, 1);
    PV_STEP(sB, 0, 2);
    PV_STEP(sB, 1, 3);
    __builtin_amdgcn_s_setprio(0);
#undef PV_STEP
  }

  // ---- epilogue: combine 4 k-quarters (arena becomes X) ----
  float den = denA + denB;
  __syncthreads();
  if (h > 0) {
    float* xp = X + ((size_t)((h - 1) * 64 + l)) * 33;
#pragma unroll
    for (int reg = 0; reg < 16; ++reg) {
      xp[reg] = oA[reg];
      xp[16 + reg] = oB[reg];
    }
    xp[32] = den;
  }
  __syncthreads();
  if (h == 0) {
#pragma unroll
    for (int p = 0; p < 3; ++p) {
      const float* xp = X + ((size_t)(p * 64 + l)) * 33;
#pragma unroll
      for (int reg = 0; reg < 16; ++reg) {
        oA[reg] += xp[reg];
        oB[reg] += xp[16 + reg];
      }
      den += xp[32];
    }
    den += __shfl_xor(den, 32);
    if (l < 32) den_s[m31] = 1.0f / den;
    float* ob = out + ((size_t)b * LQ + qbase) * DIM;
#pragma unroll
    for (int reg = 0; reg < 16; ++reg) {
      const int qr2 = (reg & 3) + 8 * (reg >> 2) + hi * 4;
      const float inv = den_s[qr2];
      ob[qr2 * DIM + m31] = oA[reg] * inv;
      ob[qr2 * DIM + 32 + m31] = oB[reg] * inv;
    }
  }
}

}  // namespace

extern "C" void kernel_launch(void* const* d_in, const int* in_sizes, int n_in,
                              void* d_out, int out_size, void* d_ws,
                              size_t ws_size, hipStream_t stream) {
  const float* q = (const float*)d_in[0];
  const float* k = (const float*)d_in[1];
  const float* v = (const float*)d_in[2];
  const uint32_t* mask = (const uint32_t*)d_in[3];
  float* out = (float*)d_out;
  int* flag = (int*)d_ws;
  unsigned short* kf_g = (unsigned short*)((char*)d_ws + WS_KF);
  unsigned short* vt_g = (unsigned short*)((char*)d_ws + WS_VT);

  prep_kv<<<321, 256, 0, stream>>>(k, v, mask, flag, kf_g, vt_g);
  attn_mfma<<<dim3(1024), 256, 0, stream>>>(q, kf_g, vt_g, mask, flag, out);
}